// Round 1
// baseline (385.085 us; speedup 1.0000x reference)
//
#include <hip/hip_runtime.h>
#include <hip/hip_bf16.h>
#include <stdint.h>

typedef __bf16 bf16x8 __attribute__((ext_vector_type(8)));
typedef float f32x4 __attribute__((ext_vector_type(4)));

__device__ __forceinline__ ushort f2bf(float f) {
  uint32_t u = __builtin_bit_cast(uint32_t, f);
  u += 0x7FFFu + ((u >> 16) & 1u);   // RNE
  return (ushort)(u >> 16);
}

__device__ __forceinline__ void gload16(const void* g, void* l) {
  auto gp = reinterpret_cast<const __attribute__((address_space(1))) char*>(
      reinterpret_cast<uintptr_t>(g));
  auto lp = reinterpret_cast<__attribute__((address_space(3))) char*>(
      reinterpret_cast<uintptr_t>(l));
  __builtin_amdgcn_global_load_lds(gp, lp, 16, 0, 0);
}

__device__ __forceinline__ f32x4 mfma16(bf16x8 a, bf16x8 b, f32x4 c) {
  return __builtin_amdgcn_mfma_f32_16x16x32_bf16(a, b, c, 0, 0, 0);
}

// ---------------- cast fp32 -> bf16 ----------------
__global__ void cast_kernel(const float* __restrict__ src, ushort* __restrict__ dst) {
  int i = (blockIdx.x * 256 + threadIdx.x) * 4;
  float4 v = *(const float4*)(src + i);
  ushort4 o;
  o.x = f2bf(v.x); o.y = f2bf(v.y); o.z = f2bf(v.z); o.w = f2bf(v.w);
  *(ushort4*)(dst + i) = o;
}

// ---------------- GEMM: C = A[M,1024] * W[N,1024]^T (+bias) ----------------
// MODE 0: QKV projection, N=3072. Scatters Q,K -> [B,H,S,64] bf16 (Q pre-scaled
//         by 0.125), V -> [B,H,64,S] bf16 (transposed for attention).
// MODE 1: out projection, N=1024, fp32 output [M,1024] + bias.
template <int MODE>
__global__ __launch_bounds__(256) void gemm_k(
    const ushort* __restrict__ A, const ushort* __restrict__ W,
    const float* __restrict__ b0, const float* __restrict__ b1,
    const float* __restrict__ b2,
    ushort* __restrict__ qo, ushort* __restrict__ ko, ushort* __restrict__ vo,
    float* __restrict__ fo)
{
  __shared__ ushort As[128 * 64];
  __shared__ ushort Bs[128 * 64];
  const int tid = threadIdx.x;
  const int lane = tid & 63, wv = tid >> 6;
  const int wr = wv >> 1, wc = wv & 1;
  const int l15 = lane & 15, l4 = lane >> 4;
  const int m0 = blockIdx.y * 128, n0 = blockIdx.x * 128;

  f32x4 acc[4][4];
  const f32x4 zero = {0.f, 0.f, 0.f, 0.f};
#pragma unroll
  for (int i = 0; i < 4; ++i)
#pragma unroll
    for (int j = 0; j < 4; ++j) acc[i][j] = zero;

  const int soff = wv * 1024 + lane * 16;                  // staging byte offset
  const int a_base = (wr * 64 + l15) * 128 + l4 * 16;      // LDS frag byte offset
  const int b_base = (wc * 64 + l15) * 128 + l4 * 16;
  const char* Ag = (const char*)(A + (size_t)m0 * 1024);
  const char* Wg = (const char*)(W + (size_t)n0 * 1024);

  for (int kt = 0; kt < 16; ++kt) {
    const int k0b = kt * 128;  // 64 k-elems = 128 bytes
#pragma unroll
    for (int sh = 0; sh < 4; ++sh) {
      int off = soff + sh * 4096;
      int row = off >> 7, colb = off & 127;
      gload16(Ag + (size_t)row * 2048 + k0b + colb, (char*)As + off);
      gload16(Wg + (size_t)row * 2048 + k0b + colb, (char*)Bs + off);
    }
    __syncthreads();
#pragma unroll
    for (int kk = 0; kk < 2; ++kk) {
      bf16x8 af[4], bfr[4];
#pragma unroll
      for (int mt = 0; mt < 4; ++mt)
        af[mt] = *(const bf16x8*)((const char*)As + a_base + mt * 2048 + kk * 64);
#pragma unroll
      for (int nt = 0; nt < 4; ++nt)
        bfr[nt] = *(const bf16x8*)((const char*)Bs + b_base + nt * 2048 + kk * 64);
#pragma unroll
      for (int mt = 0; mt < 4; ++mt)
#pragma unroll
        for (int nt = 0; nt < 4; ++nt)
          acc[mt][nt] = mfma16(af[mt], bfr[nt], acc[mt][nt]);
    }
    __syncthreads();
  }

  if (MODE == 0) {
#pragma unroll
    for (int nt = 0; nt < 4; ++nt) {
      int n = n0 + wc * 64 + nt * 16 + l15;
      int seg = n >> 10, nl = n & 1023;
      int h = nl >> 6, d = nl & 63;
      const float* bptr = (seg == 0) ? b0 : (seg == 1) ? b1 : b2;
      float bias = bptr[nl];
#pragma unroll
      for (int mt = 0; mt < 4; ++mt) {
        int m = m0 + wr * 64 + mt * 16 + l4 * 4;
        int b = m >> 11, s = m & 2047;
        if (seg == 2) {
          ushort4 pk;
          pk.x = f2bf(acc[mt][nt][0] + bias);
          pk.y = f2bf(acc[mt][nt][1] + bias);
          pk.z = f2bf(acc[mt][nt][2] + bias);
          pk.w = f2bf(acc[mt][nt][3] + bias);
          *(ushort4*)(vo + (size_t)((b * 16 + h) * 64 + d) * 2048 + s) = pk;
        } else {
          ushort* dst = (seg == 0) ? qo : ko;
          float sc = (seg == 0) ? 0.125f : 1.0f;  // fold 1/sqrt(64) into Q (exact in bf16)
#pragma unroll
          for (int r = 0; r < 4; ++r)
            dst[(size_t)((b * 16 + h) * 2048 + s + r) * 64 + d] =
                f2bf((acc[mt][nt][r] + bias) * sc);
        }
      }
    }
  } else {
#pragma unroll
    for (int nt = 0; nt < 4; ++nt) {
      int n = n0 + wc * 64 + nt * 16 + l15;
      float bias = b0[n];
#pragma unroll
      for (int mt = 0; mt < 4; ++mt) {
        int m = m0 + wr * 64 + mt * 16 + l4 * 4;
#pragma unroll
        for (int r = 0; r < 4; ++r)
          fo[(size_t)(m + r) * 1024 + n] = acc[mt][nt][r] + bias;
      }
    }
  }
}

// ---------------- flash attention ----------------
// Q,K: [B,H,S,64] bf16 (Q pre-scaled), V: [B,H,64,S] bf16 (transposed).
// O: [B,S,H*64] bf16. Block: 128 q-rows (4 waves x 32), KV tile 64.
__global__ __launch_bounds__(256) void attn_k(
    const ushort* __restrict__ Q, const ushort* __restrict__ K,
    const ushort* __restrict__ V, ushort* __restrict__ O)
{
  __shared__ ushort Ks[64 * 64];
  __shared__ ushort Vs[64 * 64];
  __shared__ ushort Ps[4 * 32 * 64];
  const int tid = threadIdx.x, lane = tid & 63, w = tid >> 6;
  const int l15 = lane & 15, l4 = lane >> 4;
  const int bh = blockIdx.y;
  const int q0 = blockIdx.x * 128;
  const int b = bh >> 4, h = bh & 15;
  const ushort* Qh = Q + (size_t)bh * 131072;
  const ushort* Kh = K + (size_t)bh * 131072;
  const ushort* Vh = V + (size_t)bh * 131072;

  bf16x8 qf[2][2];
#pragma unroll
  for (int mt = 0; mt < 2; ++mt)
#pragma unroll
    for (int kk = 0; kk < 2; ++kk)
      qf[mt][kk] = *(const bf16x8*)(Qh + (size_t)(q0 + w * 32 + mt * 16 + l15) * 64 +
                                    kk * 32 + l4 * 8);

  f32x4 oacc[2][4];
  float mrun[2][4], lrun[2][4];
  const f32x4 zero = {0.f, 0.f, 0.f, 0.f};
#pragma unroll
  for (int mt = 0; mt < 2; ++mt) {
#pragma unroll
    for (int dt = 0; dt < 4; ++dt) oacc[mt][dt] = zero;
#pragma unroll
    for (int r = 0; r < 4; ++r) { mrun[mt][r] = -INFINITY; lrun[mt][r] = 0.f; }
  }

  const int soff = w * 1024 + lane * 16;

  for (int j = 0; j < 32; ++j) {
    const int t0 = j * 64;
#pragma unroll
    for (int sh = 0; sh < 2; ++sh) {
      int off = soff + sh * 4096;
      gload16((const char*)(Kh + (size_t)t0 * 64) + off, (char*)Ks + off);
      int d = off >> 7, colb = off & 127;
      gload16((const char*)(Vh + (size_t)d * 2048 + t0) + colb, (char*)Vs + off);
    }
    __syncthreads();

    f32x4 sacc[2][4];
#pragma unroll
    for (int mt = 0; mt < 2; ++mt)
#pragma unroll
      for (int nt = 0; nt < 4; ++nt) sacc[mt][nt] = zero;

#pragma unroll
    for (int kk = 0; kk < 2; ++kk) {
      bf16x8 kf[4];
#pragma unroll
      for (int nt = 0; nt < 4; ++nt)
        kf[nt] = *(const bf16x8*)((const char*)Ks + (nt * 16 + l15) * 128 + kk * 64 + l4 * 16);
#pragma unroll
      for (int mt = 0; mt < 2; ++mt)
#pragma unroll
        for (int nt = 0; nt < 4; ++nt)
          sacc[mt][nt] = mfma16(qf[mt][kk], kf[nt], sacc[mt][nt]);
    }

    // online softmax (scores pre-scaled via Q)
#pragma unroll
    for (int mt = 0; mt < 2; ++mt) {
      float mx[4], rs[4];
#pragma unroll
      for (int r = 0; r < 4; ++r) {
        float v = fmaxf(fmaxf(sacc[mt][0][r], sacc[mt][1][r]),
                        fmaxf(sacc[mt][2][r], sacc[mt][3][r]));
        mx[r] = v;
      }
#pragma unroll
      for (int msk = 1; msk <= 8; msk <<= 1)
#pragma unroll
        for (int r = 0; r < 4; ++r) mx[r] = fmaxf(mx[r], __shfl_xor(mx[r], msk));
#pragma unroll
      for (int r = 0; r < 4; ++r) {
        float mnew = fmaxf(mrun[mt][r], mx[r]);
        float f = __expf(mrun[mt][r] - mnew);
        mrun[mt][r] = mnew;
        lrun[mt][r] *= f;
#pragma unroll
        for (int dt = 0; dt < 4; ++dt) oacc[mt][dt][r] *= f;
        float s = 0.f;
#pragma unroll
        for (int nt = 0; nt < 4; ++nt) {
          float p = __expf(sacc[mt][nt][r] - mnew);
          sacc[mt][nt][r] = p;
          s += p;
        }
        rs[r] = s;
      }
#pragma unroll
      for (int msk = 1; msk <= 8; msk <<= 1)
#pragma unroll
        for (int r = 0; r < 4; ++r) rs[r] += __shfl_xor(rs[r], msk);
#pragma unroll
      for (int r = 0; r < 4; ++r) lrun[mt][r] += rs[r];
      // P (D-layout) -> LDS, re-read in A-layout
#pragma unroll
      for (int nt = 0; nt < 4; ++nt)
#pragma unroll
        for (int r = 0; r < 4; ++r)
          Ps[w * 2048 + (mt * 16 + l4 * 4 + r) * 64 + nt * 16 + l15] =
              f2bf(sacc[mt][nt][r]);
    }

    // PV
#pragma unroll
    for (int kk = 0; kk < 2; ++kk) {
      bf16x8 pf[2], vf[4];
#pragma unroll
      for (int mt = 0; mt < 2; ++mt)
        pf[mt] = *(const bf16x8*)(Ps + w * 2048 + (mt * 16 + l15) * 64 + kk * 32 + l4 * 8);
#pragma unroll
      for (int dt = 0; dt < 4; ++dt)
        vf[dt] = *(const bf16x8*)((const char*)Vs + (dt * 16 + l15) * 128 + kk * 64 + l4 * 16);
#pragma unroll
      for (int mt = 0; mt < 2; ++mt)
#pragma unroll
        for (int dt = 0; dt < 4; ++dt)
          oacc[mt][dt] = mfma16(pf[mt], vf[dt], oacc[mt][dt]);
    }
    __syncthreads();
  }

#pragma unroll
  for (int mt = 0; mt < 2; ++mt)
#pragma unroll
    for (int dt = 0; dt < 4; ++dt) {
      int d = dt * 16 + l15;
#pragma unroll
      for (int r = 0; r < 4; ++r) {
        int q = q0 + w * 32 + mt * 16 + l4 * 4 + r;
        O[(size_t)(b * 2048 + q) * 1024 + h * 64 + d] = f2bf(oacc[mt][dt][r] / lrun[mt][r]);
      }
    }
}

extern "C" void kernel_launch(void* const* d_in, const int* in_sizes, int n_in,
                              void* d_out, int out_size, void* d_ws, size_t ws_size,
                              hipStream_t stream)
{
  const float* x  = (const float*)d_in[0];
  const float* Wq = (const float*)d_in[1];
  const float* bq = (const float*)d_in[2];
  const float* Wk = (const float*)d_in[3];
  const float* bk = (const float*)d_in[4];
  const float* Wv = (const float*)d_in[5];
  const float* bv = (const float*)d_in[6];
  const float* Wo = (const float*)d_in[7];
  const float* bo = (const float*)d_in[8];
  float* out = (float*)d_out;
  ushort* ws = (ushort*)d_ws;

  // workspace layout (ushort elements); total 75,497,472 bytes
  ushort* xb   = ws;             // x bf16 [8192,1024]; later reused as attn-out
  ushort* wqkv = ws + 8388608;   // [3072,1024]
  ushort* wo   = ws + 11534336;  // [1024,1024]
  ushort* qb   = ws + 12582912;  // [B,H,S,64]
  ushort* kb   = ws + 20971520;  // [B,H,S,64]
  ushort* vb   = ws + 29360128;  // [B,H,64,S]

  cast_kernel<<<8192, 256, 0, stream>>>(x, xb);
  cast_kernel<<<1024, 256, 0, stream>>>(Wq, wqkv);
  cast_kernel<<<1024, 256, 0, stream>>>(Wk, wqkv + 1048576);
  cast_kernel<<<1024, 256, 0, stream>>>(Wv, wqkv + 2097152);
  cast_kernel<<<1024, 256, 0, stream>>>(Wo, wo);

  gemm_k<0><<<dim3(24, 64), 256, 0, stream>>>(xb, wqkv, bq, bk, bv, qb, kb, vb, nullptr);
  attn_k<<<dim3(16, 64), 256, 0, stream>>>(qb, kb, vb, xb);
  gemm_k<1><<<dim3(8, 64), 256, 0, stream>>>(xb, wo, bo, bo, bo, nullptr, nullptr, nullptr, out);
}